// Round 1
// baseline (15195.457 us; speedup 1.0000x reference)
//
#include <hip/hip_runtime.h>
#include <hip/hip_cooperative_groups.h>

// ---------------------------------------------------------------------------
// Seq2Seq (encoder 2-layer LSTM x400 steps + buggy-decoder + attention + vocab
// projection) for MI355X / gfx950.
//
// Strategy:
//   * bf16 storage / MFMA 16x16x32 with f32 accumulation everywhere.
//   * Precompute X@Wih0^T for all 400 steps with one big GEMM (no recurrence).
//   * Persistent cooperative kernel for the recurrence: 256 WGs (1 per CU),
//     weights LDS-resident bf16 (XOR-swizzled), layer0/layer1 software
//     pipelined -> 1 grid.sync per timestep.
//   * Decoder (all 16 steps independent due to source bug) + attention +
//     32000-dim projection via the shared tiled GEMM.
// ---------------------------------------------------------------------------

typedef __attribute__((ext_vector_type(8))) short bf16x8;
typedef __attribute__((ext_vector_type(4))) float f32x4;
typedef __attribute__((ext_vector_type(4))) unsigned short u16x4;

#define DEV static __device__ __forceinline__

DEV unsigned short f2bf(float f) {
  unsigned int u = __float_as_uint(f);
  u += 0x7fffu + ((u >> 16) & 1u);          // RNE
  return (unsigned short)(u >> 16);
}
DEV float bf2f(unsigned short h) { return __uint_as_float(((unsigned int)h) << 16); }
DEV float fast_sigm(float x) {
  x = fminf(fmaxf(x, -30.f), 30.f);
  return 1.f / (1.f + __expf(-x));
}
DEV float fast_tanh(float x) {
  x = fminf(fmaxf(x, -15.f), 15.f);
  float e = __expf(2.f * x);
  return (e - 1.f) / (e + 1.f);
}

#define GLD16(gp, lp) __builtin_amdgcn_global_load_lds( \
    (const __attribute__((address_space(1))) void*)(gp), \
    (__attribute__((address_space(3))) void*)(lp), 16, 0, 0)

// ---------------------------------------------------------------------------
// Generic C[m][n] = act(sum_k A[m][k]*B[n][k] + bias[n]); A:[M][K] B:[N][K]
// bf16 row-major. 128x128 tile, BK=64, 4 waves. Requires K%64==0, N%128==0.
// M arbitrary (clamped loads, predicated stores).
// ---------------------------------------------------------------------------
template <int OUT_F32, int ACT_TANH>
__global__ __launch_bounds__(256) void gemm_bt(
    const unsigned short* __restrict__ A, const unsigned short* __restrict__ B,
    void* __restrict__ Cv, const float* __restrict__ bias, int M, int N, int K) {
  __shared__ unsigned short As[128 * 64];
  __shared__ unsigned short Bs[128 * 64];
  const int tid = threadIdx.x;
  const int wave = tid >> 6, lane = tid & 63;
  const int m0 = blockIdx.y * 128, n0 = blockIdx.x * 128;
  const int wm = wave & 1, wn = wave >> 1;
  const int lr = lane & 15, lc = lane >> 4;

  f32x4 acc[4][4];
#pragma unroll
  for (int i = 0; i < 4; ++i)
#pragma unroll
    for (int j = 0; j < 4; ++j) acc[i][j] = (f32x4){0.f, 0.f, 0.f, 0.f};

  const int nk = K >> 6;
  for (int kt = 0; kt < nk; ++kt) {
    // stage A[128][64] and B[128][64] (16KB each), swizzled via pre-swizzled
    // global source (linear LDS dest as global_load_lds requires).
#pragma unroll
    for (int q = 0; q < 4; ++q) {
      const int off = q * 4096 + wave * 1024 + lane * 16;  // byte off in tile
      const int r = off >> 7;
      const int c = ((off >> 4) & 7) ^ (r & 7);
      int ga = m0 + r; if (ga >= M) ga = M - 1;
      const unsigned short* pa = A + (size_t)ga * K + kt * 64 + c * 8;
      const unsigned short* pb = B + (size_t)(n0 + r) * K + kt * 64 + c * 8;
      const int ldsoff = (q * 4096 + wave * 1024) >> 1;   // halfword idx
      GLD16(pa, As + ldsoff);
      GLD16(pb, Bs + ldsoff);
    }
    __syncthreads();
#pragma unroll
    for (int kh = 0; kh < 2; ++kh) {
      bf16x8 av[4], bv[4];
#pragma unroll
      for (int i = 0; i < 4; ++i) {
        const int ra = wm * 64 + i * 16 + lr;
        const int ca = (lc + kh * 4) ^ (ra & 7);
        av[i] = *(const bf16x8*)(As + ra * 64 + ca * 8);
        const int rb = wn * 64 + i * 16 + lr;
        const int cbs = (lc + kh * 4) ^ (rb & 7);
        bv[i] = *(const bf16x8*)(Bs + rb * 64 + cbs * 8);
      }
#pragma unroll
      for (int i = 0; i < 4; ++i)
#pragma unroll
        for (int j = 0; j < 4; ++j)
          acc[i][j] = __builtin_amdgcn_mfma_f32_16x16x32_bf16(av[i], bv[j], acc[i][j], 0, 0, 0);
    }
    __syncthreads();
  }
  // epilogue: C/D layout col=lane&15, row=(lane>>4)*4+q  [HW-verified]
#pragma unroll
  for (int i = 0; i < 4; ++i)
#pragma unroll
    for (int j = 0; j < 4; ++j)
#pragma unroll
      for (int q = 0; q < 4; ++q) {
        const int m = m0 + wm * 64 + i * 16 + lc * 4 + q;
        const int n = n0 + wn * 64 + j * 16 + lr;
        if (m < M) {
          float v = acc[i][j][q];
          if (bias) v += bias[n];
          if (ACT_TANH) v = fast_tanh(v);
          if (OUT_F32)
            ((float*)Cv)[(size_t)m * N + n] = v;
          else
            ((unsigned short*)Cv)[(size_t)m * N + n] = f2bf(v);
        }
      }
}

// ---------------------------------------------------------------------------
// Persistent encoder: 256 WGs x 256 thr. WG<128: layer0 slice (8 hidden
// units = 32 gate rows, K=1024). WG>=128: layer1 slice (K=2048, [Wih1|Whh1]).
// Pipelined: phase p computes L0 step p and L1 step p-1; one grid.sync/phase.
// ---------------------------------------------------------------------------
__global__ __launch_bounds__(256) void encoder_kernel(
    const unsigned short* __restrict__ X0g,  // [12800][4096], row=b*400+t (incl bias)
    const float* __restrict__ bias1,         // [4096] = ebih1+ebhh1
    const float* __restrict__ Whh0,          // [4096][1024] f32
    const float* __restrict__ Wih1,          // [4096][1024] f32
    const float* __restrict__ Whh1,          // [4096][1024] f32
    unsigned short* h0b,                     // [2][32][1024] bf16 ring
    unsigned short* h1b,                     // [2][32][1024]
    unsigned short* enc_out,                 // [32][448][1024] bf16
    float* c0T, float* c1T) {                // [32][1024] f32 finals
  extern __shared__ char smem[];
  const int wg = blockIdx.x;
  const bool isL1 = wg >= 128;
  const int slice = isL1 ? (wg - 128) : wg;
  const int jb = slice * 8;
  const int KW = isL1 ? 2048 : 1024;
  const int kwsh = isL1 ? 11 : 10;
  unsigned short* Ws = (unsigned short*)smem;
  float* gbuf = (float*)(smem + (size_t)32 * KW * 2);

  const int tid = threadIdx.x;
  // --- load weight slice, f32 -> bf16, XOR-swizzled rows (Guideline 4) ---
  for (int idx = tid; idx < 32 * KW; idx += 256) {
    const int r = idx >> kwsh;
    const int k = idx & (KW - 1);
    const int grow = (r >> 3) * 1024 + jb + (r & 7);  // gate-major global row
    float w;
    if (!isL1)
      w = Whh0[(size_t)grow * 1024 + k];
    else
      w = (k < 1024) ? Wih1[(size_t)grow * 1024 + k]
                     : Whh1[(size_t)grow * 1024 + (k - 1024)];
    const int c = k >> 3, jj = k & 7;
    Ws[r * KW + (((c ^ (r & 7)) << 3) + jj)] = f2bf(w);
  }
  __syncthreads();

  const int wave = tid >> 6, lane = tid & 63;
  const int Mt = wave & 1, Nt = wave >> 1;
  const int lr = lane & 15, lc = lane >> 4;
  const int arow = Mt * 16 + lr;   // batch row for A frags
  const int brow = Nt * 16 + lr;   // gate row for B frags
  const int cbt = tid >> 3, cu = tid & 7;  // cell ownership (batch, unit)
  float cst = 0.f;

  cooperative_groups::grid_group grid = cooperative_groups::this_grid();

  for (int p = 0; p <= 400; ++p) {
    const bool act = isL1 ? (p >= 1) : (p < 400);
    const int t = isL1 ? (p - 1) : p;
    f32x4 acc = (f32x4){0.f, 0.f, 0.f, 0.f};
    if (act) {
      if (!isL1) {
        const unsigned short* hp = h0b + (((t + 1) & 1) << 15) + arow * 1024 + lc * 8;
        bf16x8 a[32];
#pragma unroll
        for (int ks = 0; ks < 32; ++ks) a[ks] = *(const bf16x8*)(hp + ks * 32);
#pragma unroll
        for (int ks = 0; ks < 32; ++ks) {
          const int c = ks * 4 + lc;
          bf16x8 b = *(const bf16x8*)(Ws + brow * 1024 + ((c ^ (brow & 7)) << 3));
          acc = __builtin_amdgcn_mfma_f32_16x16x32_bf16(a[ks], b, acc, 0, 0, 0);
        }
      } else {
        const unsigned short* h0c = h0b + ((t & 1) << 15) + arow * 1024 + lc * 8;
        const unsigned short* h1p = h1b + (((t + 1) & 1) << 15) + arow * 1024 + lc * 8;
        bf16x8 a[32];
#pragma unroll
        for (int ks = 0; ks < 32; ++ks) a[ks] = *(const bf16x8*)(h0c + ks * 32);
#pragma unroll
        for (int ks = 0; ks < 32; ++ks) {
          const int c = ks * 4 + lc;
          bf16x8 b = *(const bf16x8*)(Ws + brow * 2048 + ((c ^ (brow & 7)) << 3));
          acc = __builtin_amdgcn_mfma_f32_16x16x32_bf16(a[ks], b, acc, 0, 0, 0);
        }
#pragma unroll
        for (int ks = 0; ks < 32; ++ks) a[ks] = *(const bf16x8*)(h1p + ks * 32);
#pragma unroll
        for (int ks = 0; ks < 32; ++ks) {
          const int c = (ks + 32) * 4 + lc;
          bf16x8 b = *(const bf16x8*)(Ws + brow * 2048 + ((c ^ (brow & 7)) << 3));
          acc = __builtin_amdgcn_mfma_f32_16x16x32_bf16(a[ks], b, acc, 0, 0, 0);
        }
      }
#pragma unroll
      for (int q = 0; q < 4; ++q)
        gbuf[(Mt * 16 + lc * 4 + q) * 32 + brow] = acc[q];
    }
    __syncthreads();
    if (act) {
      const int base = cbt * 32;
      float gi = gbuf[base + cu], gf = gbuf[base + 8 + cu];
      float gg = gbuf[base + 16 + cu], go = gbuf[base + 24 + cu];
      const int jg = jb + cu;
      if (!isL1) {
        const unsigned short* xg = X0g + ((size_t)(cbt * 400 + t)) * 4096;
        gi += bf2f(xg[jg]);        gf += bf2f(xg[1024 + jg]);
        gg += bf2f(xg[2048 + jg]); go += bf2f(xg[3072 + jg]);
      } else {
        gi += bias1[jg];        gf += bias1[1024 + jg];
        gg += bias1[2048 + jg]; go += bias1[3072 + jg];
      }
      const float fi = fast_sigm(gi), ff = fast_sigm(gf);
      const float fg = fast_tanh(gg), fo = fast_sigm(go);
      cst = ff * cst + fi * fg;
      const float h = fo * fast_tanh(cst);
      const unsigned short hb = f2bf(h);
      if (!isL1) {
        h0b[((t & 1) << 15) + cbt * 1024 + jg] = hb;
        if (t == 399) c0T[cbt * 1024 + jg] = cst;
      } else {
        h1b[((t & 1) << 15) + cbt * 1024 + jg] = hb;
        enc_out[((size_t)cbt * 448 + t) * 1024 + jg] = hb;
        if (t == 399) c1T[cbt * 1024 + jg] = cst;
      }
    }
    grid.sync();
  }
}

// ---------------------------------------------------------------------------
// glue kernels
// ---------------------------------------------------------------------------
__global__ __launch_bounds__(256) void cvt_bf16(const float* __restrict__ in,
                                                unsigned short* __restrict__ out,
                                                int n4) {
  int i = blockIdx.x * 256 + threadIdx.x;
  if (i < n4) {
    const float4 v = ((const float4*)in)[i];
    u16x4 o;
    o.x = f2bf(v.x); o.y = f2bf(v.y); o.z = f2bf(v.z); o.w = f2bf(v.w);
    ((u16x4*)out)[i] = o;
  }
}

__global__ __launch_bounds__(256) void add_vec(const float* a, const float* b, float* o) {
  int i = blockIdx.x * 256 + threadIdx.x;
  o[i] = a[i] + b[i];
}

__global__ __launch_bounds__(256) void gather_enc_emb(const int* __restrict__ tok,
                                                      const float* __restrict__ emb,
                                                      unsigned short* __restrict__ X) {
  const int m = blockIdx.x;           // 12800 = b*400+t
  const int t = threadIdx.x;          // 256, 2 elems each
  const int id = tok[m];
  const float2 v = ((const float2*)(emb + (size_t)id * 512))[t];
  X[(size_t)m * 512 + 2 * t] = f2bf(v.x);
  X[(size_t)m * 512 + 2 * t + 1] = f2bf(v.y);
}

__global__ __launch_bounds__(256) void gather_dec_emb(const int* __restrict__ titles,
                                                      const float* __restrict__ emb,
                                                      unsigned short* __restrict__ X) {
  const int m = blockIdx.x;           // 512 = b*16+t
  const int b = m >> 4, t = m & 15;
  const int id = (t == 0) ? 2 : titles[b * 16 + t];   // SOS then titles[:,1:]
  const float2 v = ((const float2*)(emb + (size_t)id * 512))[threadIdx.x];
  X[(size_t)m * 512 + 2 * threadIdx.x] = f2bf(v.x);
  X[(size_t)m * 512 + 2 * threadIdx.x + 1] = f2bf(v.y);
}

// decoder single-step cell (all 16 steps independent; hterm includes biases)
__global__ __launch_bounds__(256) void dec_cell(const float* __restrict__ ginp,   // [512][4096]
                                                const float* __restrict__ hterm,  // [32][4096]
                                                const float* __restrict__ cT,     // [32][1024]
                                                unsigned short* __restrict__ hout, // [512][1024]
                                                unsigned short* __restrict__ concat2) {
  const int idx = blockIdx.x * 256 + threadIdx.x;  // over 512*1024
  const int m = idx >> 10, j = idx & 1023;
  const int b = m >> 4;
  const float* gr = ginp + (size_t)m * 4096;
  const float* hr = hterm + (size_t)b * 4096;
  const float gi = gr[j] + hr[j];
  const float gf = gr[1024 + j] + hr[1024 + j];
  const float gg = gr[2048 + j] + hr[2048 + j];
  const float go = gr[3072 + j] + hr[3072 + j];
  const float cn = fast_sigm(gf) * cT[b * 1024 + j] + fast_sigm(gi) * fast_tanh(gg);
  const float h = fast_sigm(go) * fast_tanh(cn);
  const unsigned short hb = f2bf(h);
  hout[idx] = hb;
  if (concat2) concat2[(size_t)m * 2048 + 1024 + j] = hb;   // concat[:,1024:]
}

// scores[b][t][s] = energy[b*16+t] . enc_out[b][s]  (MFMA, frags from global)
__global__ __launch_bounds__(256) void scores_k(const unsigned short* __restrict__ energy,
                                                const unsigned short* __restrict__ enc_out,
                                                float* __restrict__ scores) {
  const int b = blockIdx.y;
  const int wave = threadIdx.x >> 6, lane = threadIdx.x & 63;
  const int lr = lane & 15, lc = lane >> 4;
  const int s0 = blockIdx.x * 64 + wave * 16;      // < 448
  const unsigned short* ar = energy + ((size_t)b * 16 + lr) * 1024 + lc * 8;
  const unsigned short* br = enc_out + ((size_t)b * 448 + s0 + lr) * 1024 + lc * 8;
  f32x4 acc = (f32x4){0.f, 0.f, 0.f, 0.f};
#pragma unroll
  for (int kc = 0; kc < 4; ++kc) {        // 4 chunks of 8 ksteps (K=1024)
    bf16x8 a[8], bb[8];
#pragma unroll
    for (int u = 0; u < 8; ++u) {
      a[u] = *(const bf16x8*)(ar + (kc * 8 + u) * 32);
      bb[u] = *(const bf16x8*)(br + (kc * 8 + u) * 32);
    }
#pragma unroll
    for (int u = 0; u < 8; ++u)
      acc = __builtin_amdgcn_mfma_f32_16x16x32_bf16(a[u], bb[u], acc, 0, 0, 0);
  }
#pragma unroll
  for (int q = 0; q < 4; ++q) {
    const int t = lc * 4 + q;
    scores[((size_t)b * 16 + t) * 448 + s0 + lr] = acc[q];
  }
}

// row softmax over s<400 (stride 448), zeros the pad tail. 1 wave per row.
__global__ __launch_bounds__(256) void softmax_k(float* __restrict__ sc) {
  const int row = blockIdx.x * 4 + (threadIdx.x >> 6);  // 512 rows
  const int lane = threadIdx.x & 63;
  float* p = sc + (size_t)row * 448;
  float v[7];
  float mx = -1e30f;
#pragma unroll
  for (int i = 0; i < 7; ++i) {
    const int s = lane + i * 64;
    v[i] = (s < 400) ? p[s] : -1e30f;
    mx = fmaxf(mx, v[i]);
  }
#pragma unroll
  for (int m = 1; m < 64; m <<= 1) mx = fmaxf(mx, __shfl_xor(mx, m));
  float sum = 0.f;
#pragma unroll
  for (int i = 0; i < 7; ++i) {
    const int s = lane + i * 64;
    v[i] = (s < 400) ? __expf(v[i] - mx) : 0.f;
    sum += v[i];
  }
#pragma unroll
  for (int m = 1; m < 64; m <<= 1) sum += __shfl_xor(sum, m);
  const float inv = 1.f / sum;
#pragma unroll
  for (int i = 0; i < 7; ++i) p[lane + i * 64] = v[i] * inv;
}

// context[bt][e] = sum_s alpha[bt][s]*enc_out[b][s][e] -> concat[:, :1024]
__global__ __launch_bounds__(256) void context_k(const float* __restrict__ alpha,
                                                 const unsigned short* __restrict__ enc_out,
                                                 unsigned short* __restrict__ concat) {
  const int bt = blockIdx.x;          // 512
  const int b = bt >> 4;
  const int e0 = threadIdx.x * 4;
  const float* al = alpha + (size_t)bt * 448;
  const unsigned short* eb = enc_out + (size_t)b * 448 * 1024 + e0;
  float a0 = 0.f, a1 = 0.f, a2 = 0.f, a3 = 0.f;
  for (int s = 0; s < 400; ++s) {
    const float a = al[s];
    const u16x4 ev = *(const u16x4*)(eb + (size_t)s * 1024);
    a0 += a * bf2f(ev.x); a1 += a * bf2f(ev.y);
    a2 += a * bf2f(ev.z); a3 += a * bf2f(ev.w);
  }
  unsigned short* o = concat + (size_t)bt * 2048 + e0;
  o[0] = f2bf(a0); o[1] = f2bf(a1); o[2] = f2bf(a2); o[3] = f2bf(a3);
}

// ---------------------------------------------------------------------------
extern "C" void kernel_launch(void* const* d_in, const int* in_sizes, int n_in,
                              void* d_out, int out_size, void* d_ws, size_t ws_size,
                              hipStream_t stream) {
  const int* contents = (const int*)d_in[0];
  const int* titles = (const int*)d_in[1];
  const float* emb_enc = (const float*)d_in[2];
  const float* emb_dec = (const float*)d_in[3];
  const float* eWih0 = (const float*)d_in[4];
  const float* eWhh0 = (const float*)d_in[5];
  const float* ebih0 = (const float*)d_in[6];
  const float* ebhh0 = (const float*)d_in[7];
  const float* eWih1 = (const float*)d_in[8];
  const float* eWhh1 = (const float*)d_in[9];
  const float* ebih1 = (const float*)d_in[10];
  const float* ebhh1 = (const float*)d_in[11];
  const float* dWih0 = (const float*)d_in[12];
  const float* dWhh0 = (const float*)d_in[13];
  const float* dbih0 = (const float*)d_in[14];
  const float* dbhh0 = (const float*)d_in[15];
  const float* dWih1 = (const float*)d_in[16];
  const float* dWhh1 = (const float*)d_in[17];
  const float* dbih1 = (const float*)d_in[18];
  const float* dbhh1 = (const float*)d_in[19];
  const float* w_in = (const float*)d_in[20];
  const float* w_outW = (const float*)d_in[21];
  const float* w_outb = (const float*)d_in[22];
  const float* outW = (const float*)d_in[23];
  const float* outb = (const float*)d_in[24];

  char* ws = (char*)d_ws;
  size_t off = 0;
  auto alloc = [&](size_t bytes) -> void* {
    void* p = ws + off;
    off += (bytes + 255) & ~(size_t)255;
    return p;
  };

  unsigned short* wEi0 = (unsigned short*)alloc((size_t)4096 * 512 * 2);
  unsigned short* wDi0 = (unsigned short*)alloc((size_t)4096 * 512 * 2);
  unsigned short* wDh0 = (unsigned short*)alloc((size_t)4096 * 1024 * 2);
  unsigned short* wDi1 = (unsigned short*)alloc((size_t)4096 * 1024 * 2);
  unsigned short* wDh1 = (unsigned short*)alloc((size_t)4096 * 1024 * 2);
  unsigned short* wIn = (unsigned short*)alloc((size_t)1024 * 1024 * 2);
  unsigned short* wOw = (unsigned short*)alloc((size_t)1024 * 2048 * 2);
  unsigned short* wOut = (unsigned short*)alloc((size_t)32000 * 1024 * 2);
  float* be0 = (float*)alloc(4096 * 4);
  float* be1 = (float*)alloc(4096 * 4);
  float* bd0 = (float*)alloc(4096 * 4);
  float* bd1 = (float*)alloc(4096 * 4);
  unsigned short* X = (unsigned short*)alloc((size_t)12800 * 512 * 2);
  unsigned short* X0g = (unsigned short*)alloc((size_t)12800 * 4096 * 2);
  unsigned short* h0b = (unsigned short*)alloc((size_t)2 * 32 * 1024 * 2);
  unsigned short* h1b = (unsigned short*)alloc((size_t)2 * 32 * 1024 * 2);
  float* c0T = (float*)alloc((size_t)32 * 1024 * 4);
  float* c1T = (float*)alloc((size_t)32 * 1024 * 4);
  unsigned short* encO = (unsigned short*)alloc((size_t)32 * 448 * 1024 * 2);
  unsigned short* dEmb = (unsigned short*)alloc((size_t)512 * 512 * 2);
  float* ginp = (float*)alloc((size_t)512 * 4096 * 4);
  float* hterm0 = (float*)alloc((size_t)32 * 4096 * 4);
  float* hterm1 = (float*)alloc((size_t)32 * 4096 * 4);
  unsigned short* dH0 = (unsigned short*)alloc((size_t)512 * 1024 * 2);
  unsigned short* dOut = (unsigned short*)alloc((size_t)512 * 1024 * 2);
  unsigned short* energy = (unsigned short*)alloc((size_t)512 * 1024 * 2);
  float* scores = (float*)alloc((size_t)512 * 448 * 4);
  unsigned short* concat = (unsigned short*)alloc((size_t)512 * 2048 * 2);
  unsigned short* attnH = (unsigned short*)alloc((size_t)512 * 1024 * 2);

  // --- weight conversions (f32 -> bf16) ---
  auto cvt = [&](const float* src, unsigned short* dst, size_t n) {
    int n4 = (int)(n / 4);
    cvt_bf16<<<dim3((n4 + 255) / 256), dim3(256), 0, stream>>>(src, dst, n4);
  };
  cvt(eWih0, wEi0, (size_t)4096 * 512);
  cvt(dWih0, wDi0, (size_t)4096 * 512);
  cvt(dWhh0, wDh0, (size_t)4096 * 1024);
  cvt(dWih1, wDi1, (size_t)4096 * 1024);
  cvt(dWhh1, wDh1, (size_t)4096 * 1024);
  cvt(w_in, wIn, (size_t)1024 * 1024);
  cvt(w_outW, wOw, (size_t)1024 * 2048);
  cvt(outW, wOut, (size_t)32000 * 1024);

  add_vec<<<dim3(16), dim3(256), 0, stream>>>(ebih0, ebhh0, be0);
  add_vec<<<dim3(16), dim3(256), 0, stream>>>(ebih1, ebhh1, be1);
  add_vec<<<dim3(16), dim3(256), 0, stream>>>(dbih0, dbhh0, bd0);
  add_vec<<<dim3(16), dim3(256), 0, stream>>>(dbih1, dbhh1, bd1);

  gather_enc_emb<<<dim3(12800), dim3(256), 0, stream>>>(contents, emb_enc, X);
  gather_dec_emb<<<dim3(512), dim3(256), 0, stream>>>(titles, emb_dec, dEmb);
  hipMemsetAsync(h0b, 0, (size_t)2 * 32 * 1024 * 2, stream);
  hipMemsetAsync(h1b, 0, (size_t)2 * 32 * 1024 * 2, stream);

  // --- layer0 input transform for all 400 steps: X0g = X @ eWih0^T + be0 ---
  gemm_bt<0, 0><<<dim3(32, 100), dim3(256), 0, stream>>>(X, wEi0, (void*)X0g, be0,
                                                         12800, 4096, 512);

  // --- persistent recurrence ---
  const unsigned int encSmem = 32 * 2048 * 2 + 32 * 32 * 4;  // 135168
  hipFuncSetAttribute((const void*)encoder_kernel,
                      hipFuncAttributeMaxDynamicSharedMemorySize, (int)encSmem);
  {
    const unsigned short* X0g_c = X0g;
    const float* be1_c = be1;
    void* args[] = {(void*)&X0g_c, (void*)&be1_c, (void*)&eWhh0, (void*)&eWih1,
                    (void*)&eWhh1, (void*)&h0b, (void*)&h1b, (void*)&encO,
                    (void*)&c0T, (void*)&c1T};
    hipLaunchCooperativeKernel((const void*)encoder_kernel, dim3(256), dim3(256),
                               args, encSmem, stream);
  }

  // --- decoder (16 independent single steps from encoder final state) ---
  // hT[l] lives in h{0,1}b buffer index 1 (t=399 is odd).
  gemm_bt<1, 0><<<dim3(32, 1), dim3(256), 0, stream>>>(h0b + 32768, wDh0,
                                                       (void*)hterm0, bd0, 32, 4096, 1024);
  gemm_bt<1, 0><<<dim3(32, 4), dim3(256), 0, stream>>>(dEmb, wDi0, (void*)ginp,
                                                       (const float*)nullptr, 512, 4096, 512);
  dec_cell<<<dim3(2048), dim3(256), 0, stream>>>(ginp, hterm0, c0T, dH0,
                                                 (unsigned short*)nullptr);
  gemm_bt<1, 0><<<dim3(32, 1), dim3(256), 0, stream>>>(h1b + 32768, wDh1,
                                                       (void*)hterm1, bd1, 32, 4096, 1024);
  gemm_bt<1, 0><<<dim3(32, 4), dim3(256), 0, stream>>>(dH0, wDi1, (void*)ginp,
                                                       (const float*)nullptr, 512, 4096, 1024);
  dec_cell<<<dim3(2048), dim3(256), 0, stream>>>(ginp, hterm1, c1T, dOut, concat);

  // --- attention ---
  gemm_bt<0, 0><<<dim3(8, 4), dim3(256), 0, stream>>>(dOut, wIn, (void*)energy,
                                                      (const float*)nullptr, 512, 1024, 1024);
  scores_k<<<dim3(7, 32), dim3(256), 0, stream>>>(energy, encO, scores);
  softmax_k<<<dim3(128), dim3(256), 0, stream>>>(scores);
  context_k<<<dim3(512), dim3(256), 0, stream>>>(scores, encO, concat);
  gemm_bt<0, 1><<<dim3(8, 4), dim3(256), 0, stream>>>(concat, wOw, (void*)attnH,
                                                      w_outb, 512, 1024, 2048);
  // --- vocab projection -> d_out f32 [32][16][32000] ---
  gemm_bt<1, 0><<<dim3(250, 4), dim3(256), 0, stream>>>(attnH, wOut, d_out, outb,
                                                        512, 32000, 1024);
}